// Round 7
// baseline (161.248 us; speedup 1.0000x reference)
//
#include <hip/hip_runtime.h>
#include <math.h>

namespace {

typedef float f32x4 __attribute__((ext_vector_type(4)));

constexpr int A = 4;
constexpr int H = 2048;
constexpr int BLK = 256;      // 4 independent waves; one token per wave
constexpr float EPSV = 1e-6f;
constexpr float CLIPV = 120.0f;

__device__ __forceinline__ float clipv(float v) {
    return fminf(fmaxf(v, -CLIPV), CLIPV);
}

// Barrier-free: one 64-lane wave per token. 32 elems/lane (8 x f32x4).
// No LDS, no __syncthreads — waves desynchronize freely so the per-token
// shuffle/tanh bubble of one wave overlaps the HBM traffic of its neighbors.
__global__ __launch_bounds__(BLK) void altup_wave(
    const float* __restrict__ hs,        // [A,T,H]
    const float* __restrict__ act,       // [T,H]
    const float* __restrict__ rnw,       // [H]
    const float* __restrict__ w_router,  // [A,H]
    const float* __restrict__ w_pred,    // [16,4]
    const float* __restrict__ w_corr,    // [4,4]
    const float* __restrict__ oscale,    // [H]
    float* __restrict__ out,             // corrected [A,T,H] ++ output [T,H]
    int T)
{
    const int tid  = threadIdx.x;
    const int wave = tid >> 6;
    const int lane = tid & 63;
    const int t    = blockIdx.x * (BLK / 64) + wave;   // consecutive tokens per block
    const size_t TH = (size_t)T * H;
    const size_t ro = (size_t)t * H;

    // ---- phase 1: stream x0/act, accumulate 10 partials; hold x0/av in regs ----
    f32x4 x0[8], av[8];
    float part[10];
#pragma unroll
    for (int q = 0; q < 10; ++q) part[q] = 0.f;

#pragma unroll
    for (int c = 0; c < 8; ++c) {
        const int h = c * 256 + lane * 4;
        x0[c] = __builtin_nontemporal_load((const f32x4*)(hs + ro + h));
        av[c] = __builtin_nontemporal_load((const f32x4*)(act + ro + h));
        const f32x4 r  = *(const f32x4*)(rnw + h);            // L1/L2-resident
        const f32x4 w0 = *(const f32x4*)(w_router + 0 * H + h);
        const f32x4 w1 = *(const f32x4*)(w_router + 1 * H + h);
        const f32x4 w2 = *(const f32x4*)(w_router + 2 * H + h);
        const f32x4 w3 = *(const f32x4*)(w_router + 3 * H + h);
#pragma unroll
        for (int k = 0; k < 4; ++k) {
            const float x = x0[c][k], a = av[c][k], rr = r[k];
            part[0] = fmaf(x, x, part[0]);
            part[5] = fmaf(a, a, part[5]);
            const float xr = x * rr;
            const float ar = a * rr;
            part[1] = fmaf(xr, w0[k], part[1]);
            part[2] = fmaf(xr, w1[k], part[2]);
            part[3] = fmaf(xr, w2[k], part[3]);
            part[4] = fmaf(xr, w3[k], part[4]);
            part[6] = fmaf(ar, w0[k], part[6]);
            part[7] = fmaf(ar, w1[k], part[7]);
            part[8] = fmaf(ar, w2[k], part[8]);
            part[9] = fmaf(ar, w3[k], part[9]);
        }
    }

    // ---- full-wave butterfly: every lane ends with the complete sums ----
#pragma unroll
    for (int off = 32; off >= 1; off >>= 1) {
#pragma unroll
        for (int q = 0; q < 10; ++q) part[q] += __shfl_xor(part[q], off, 64);
    }

    // ---- phase 2: scalar coefficients (redundant per lane) ----
    const float invH = 1.0f / (float)H;
    const float sp = rsqrtf(part[0] * invH + EPSV) * invH;
    const float sc = rsqrtf(part[5] * invH + EPSV) * invH;
    float mp[4], mc[4];
#pragma unroll
    for (int j = 0; j < 4; ++j) {
        mp[j] = tanhf(part[1 + j] * sp);
        mc[j] = tanhf(part[6 + j] * sc);
    }

    float coef[4][4];   // coef[a][b] = sum_j mp[j]*clip(w_pred[b*4+a, j])
#pragma unroll
    for (int b = 0; b < 4; ++b)
#pragma unroll
        for (int a = 0; a < 4; ++a) {
            float s = 0.f;
#pragma unroll
            for (int j = 0; j < 4; ++j)
                s = fmaf(mp[j], clipv(w_pred[(b * 4 + a) * A + j]), s);
            coef[a][b] = s;
        }
    float cc[4];
#pragma unroll
    for (int a = 0; a < 4; ++a) {
        float s = 1.0f;
#pragma unroll
        for (int j = 0; j < 4; ++j)
            s = fmaf(mc[j], clipv(w_corr[a * A + j]), s);
        cc[a] = s;
    }

    // ---- phase 3: stream x1..x3, apply, store (all NT) ----
#pragma unroll
    for (int c = 0; c < 8; ++c) {
        const int h = c * 256 + lane * 4;
        const f32x4 x1 = __builtin_nontemporal_load((const f32x4*)(hs + 1 * TH + ro + h));
        const f32x4 x2 = __builtin_nontemporal_load((const f32x4*)(hs + 2 * TH + ro + h));
        const f32x4 x3 = __builtin_nontemporal_load((const f32x4*)(hs + 3 * TH + ro + h));
        const f32x4 sv = *(const f32x4*)(oscale + h);

        f32x4 co0, co1, co2, co3, ov;
#pragma unroll
        for (int k = 0; k < 4; ++k) {
            const float xs4[4] = {x0[c][k], x1[k], x2[k], x3[k]};
            float pr[4];
#pragma unroll
            for (int b = 0; b < 4; ++b) {
                float s = xs4[b];
#pragma unroll
                for (int a = 0; a < 4; ++a)
                    s = fmaf(xs4[a], coef[a][b], s);
                pr[b] = s;
            }
            const float innov = av[c][k] - pr[0];
            co0[k] = fmaf(innov, cc[0], pr[0]);
            co1[k] = fmaf(innov, cc[1], pr[1]);
            co2[k] = fmaf(innov, cc[2], pr[2]);
            co3[k] = fmaf(innov, cc[3], pr[3]);
            ov[k]  = co0[k] * sv[k];
        }
        __builtin_nontemporal_store(co0, (f32x4*)(out + 0 * TH + ro + h));
        __builtin_nontemporal_store(co1, (f32x4*)(out + 1 * TH + ro + h));
        __builtin_nontemporal_store(co2, (f32x4*)(out + 2 * TH + ro + h));
        __builtin_nontemporal_store(co3, (f32x4*)(out + 3 * TH + ro + h));
        __builtin_nontemporal_store(ov,  (f32x4*)(out + (size_t)A * TH + ro + h));
    }
}

}  // namespace

extern "C" void kernel_launch(void* const* d_in, const int* in_sizes, int n_in,
                              void* d_out, int out_size, void* d_ws, size_t ws_size,
                              hipStream_t stream) {
    const float* hs       = (const float*)d_in[0];
    const float* act      = (const float*)d_in[1];
    const float* rnw      = (const float*)d_in[2];
    const float* w_router = (const float*)d_in[3];
    const float* w_pred   = (const float*)d_in[4];
    const float* w_corr   = (const float*)d_in[5];
    const float* oscale   = (const float*)d_in[6];
    float* out = (float*)d_out;

    const int T = in_sizes[1] / H;          // activated is [T,H]
    const int G = T / (BLK / 64);           // 4 tokens per block (one per wave)

    altup_wave<<<dim3(G), dim3(BLK), 0, stream>>>(
        hs, act, rnw, w_router, w_pred, w_corr, oscale, out, T);
}

// Round 8
// 122.554 us; speedup vs baseline: 1.3157x; 1.3157x over previous
//
#include <hip/hip_runtime.h>
#include <math.h>

namespace {

typedef float f32x4 __attribute__((ext_vector_type(4)));

constexpr int A = 4;
constexpr int H = 2048;
constexpr int BLK = 256;            // each thread owns 8 floats = 2x float4 chunks
constexpr float EPSV = 1e-6f;
constexpr float CLIPV = 120.0f;

__device__ __forceinline__ float clipv(float v) {
    return fminf(fmaxf(v, -CLIPV), CLIPV);
}

__global__ __launch_bounds__(BLK) void altup_fused(
    const float* __restrict__ hs,        // [A,T,H]
    const float* __restrict__ act,       // [T,H]
    const float* __restrict__ rnw,       // [H]
    const float* __restrict__ w_router,  // [A,H]
    const float* __restrict__ w_pred,    // [16,4]
    const float* __restrict__ w_corr,    // [4,4]
    const float* __restrict__ oscale,    // [H]
    float* __restrict__ out,             // corrected [A,T,H] ++ output [T,H]
    int T)
{
    const int t   = blockIdx.x;
    const int tid = threadIdx.x;
    const size_t TH = (size_t)T * H;
    const size_t rowOff = (size_t)t * H;
    const int hofs[2] = {tid * 4, 1024 + tid * 4};

    // ---- issue ALL big-stream loads up front (read-once -> non-temporal) ----
    // Phase-3 data (x1..x3, oscale) is loaded BEFORE the reduction barrier so
    // the HBM pipe stays busy through the shuffle/tanh compute bubble.
    f32x4 x0[2], av[2], x1[2], x2[2], x3[2], rv[2], sv[2], wr[4][2];
#pragma unroll
    for (int c = 0; c < 2; ++c) {
        const int h = hofs[c];
        x0[c] = __builtin_nontemporal_load((const f32x4*)(hs + rowOff + h));
        av[c] = __builtin_nontemporal_load((const f32x4*)(act + rowOff + h));
        x1[c] = __builtin_nontemporal_load((const f32x4*)(hs + 1 * TH + rowOff + h));
        x2[c] = __builtin_nontemporal_load((const f32x4*)(hs + 2 * TH + rowOff + h));
        x3[c] = __builtin_nontemporal_load((const f32x4*)(hs + 3 * TH + rowOff + h));
        // block-shared small arrays: normal cached loads (L1/L2-resident)
        rv[c] = *(const f32x4*)(rnw + h);
        sv[c] = *(const f32x4*)(oscale + h);
#pragma unroll
        for (int j = 0; j < 4; ++j)
            wr[j][c] = *(const f32x4*)(w_router + j * H + h);
    }

    // ---- phase 1: 10 partial sums ----
    float part[10];
#pragma unroll
    for (int i = 0; i < 10; ++i) part[i] = 0.f;

#pragma unroll
    for (int c = 0; c < 2; ++c) {
#pragma unroll
        for (int k = 0; k < 4; ++k) {
            const float x = x0[c][k], a = av[c][k], r = rv[c][k];
            part[0] = fmaf(x, x, part[0]);
            part[5] = fmaf(a, a, part[5]);
            const float xr = x * r;
            const float ar = a * r;
            part[1] = fmaf(xr, wr[0][c][k], part[1]);
            part[2] = fmaf(xr, wr[1][c][k], part[2]);
            part[3] = fmaf(xr, wr[2][c][k], part[3]);
            part[4] = fmaf(xr, wr[3][c][k], part[4]);
            part[6] = fmaf(ar, wr[0][c][k], part[6]);
            part[7] = fmaf(ar, wr[1][c][k], part[7]);
            part[8] = fmaf(ar, wr[2][c][k], part[8]);
            part[9] = fmaf(ar, wr[3][c][k], part[9]);
        }
    }

    // ---- wave(64) shuffle reduce + 4-wave LDS combine ----
#pragma unroll
    for (int off = 32; off >= 1; off >>= 1) {
#pragma unroll
        for (int i = 0; i < 10; ++i) part[i] += __shfl_down(part[i], off, 64);
    }

    __shared__ float red[BLK / 64][10];
    const int wave = tid >> 6;
    const int lane = tid & 63;
    if (lane == 0) {
#pragma unroll
        for (int i = 0; i < 10; ++i) red[wave][i] = part[i];
    }
    __syncthreads();

    float sums[10];
#pragma unroll
    for (int i = 0; i < 10; ++i)
        sums[i] = red[0][i] + red[1][i] + red[2][i] + red[3][i];

    // ---- phase 2: scalar coefficients (redundant per thread) ----
    const float invH = 1.0f / (float)H;
    const float sp = rsqrtf(sums[0] * invH + EPSV) * invH;
    const float sc = rsqrtf(sums[5] * invH + EPSV) * invH;
    float mp[4], mc[4];
#pragma unroll
    for (int j = 0; j < 4; ++j) {
        mp[j] = tanhf(sums[1 + j] * sp);
        mc[j] = tanhf(sums[6 + j] * sc);
    }

    // coef[a][b] = sum_j mp[j]*clip(w_pred[b*4+a, j])  (reshape+transpose folded)
    float coef[4][4];
#pragma unroll
    for (int b = 0; b < 4; ++b) {
#pragma unroll
        for (int a = 0; a < 4; ++a) {
            float s = 0.f;
#pragma unroll
            for (int j = 0; j < 4; ++j)
                s = fmaf(mp[j], clipv(w_pred[(b * 4 + a) * A + j]), s);
            coef[a][b] = s;
        }
    }
    float cc[4];
#pragma unroll
    for (int a = 0; a < 4; ++a) {
        float s = 1.0f;
#pragma unroll
        for (int j = 0; j < 4; ++j)
            s = fmaf(mc[j], clipv(w_corr[a * A + j]), s);
        cc[a] = s;
    }

    // ---- phase 3: pointwise predict/correct/scale; non-temporal stores ----
#pragma unroll
    for (int c = 0; c < 2; ++c) {
        const int h = hofs[c];
        f32x4 co[4], ov;
#pragma unroll
        for (int k = 0; k < 4; ++k) {
            const float xs4[4] = {x0[c][k], x1[c][k], x2[c][k], x3[c][k]};
            float pr[4];
#pragma unroll
            for (int b = 0; b < 4; ++b) {
                float s = xs4[b];
#pragma unroll
                for (int a = 0; a < 4; ++a)
                    s = fmaf(xs4[a], coef[a][b], s);
                pr[b] = s;
            }
            const float innov = av[c][k] - pr[0];
#pragma unroll
            for (int a = 0; a < 4; ++a)
                co[a][k] = fmaf(innov, cc[a], pr[a]);
            ov[k] = co[0][k] * sv[c][k];
        }
#pragma unroll
        for (int a = 0; a < 4; ++a)
            __builtin_nontemporal_store(co[a], (f32x4*)(out + (size_t)a * TH + rowOff + h));
        __builtin_nontemporal_store(ov, (f32x4*)(out + (size_t)A * TH + rowOff + h));
    }
}

}  // namespace

extern "C" void kernel_launch(void* const* d_in, const int* in_sizes, int n_in,
                              void* d_out, int out_size, void* d_ws, size_t ws_size,
                              hipStream_t stream) {
    const float* hs       = (const float*)d_in[0];
    const float* act      = (const float*)d_in[1];
    const float* rnw      = (const float*)d_in[2];
    const float* w_router = (const float*)d_in[3];
    const float* w_pred   = (const float*)d_in[4];
    const float* w_corr   = (const float*)d_in[5];
    const float* oscale   = (const float*)d_in[6];
    float* out = (float*)d_out;

    const int T = in_sizes[1] / H;  // activated is [T,H]

    altup_fused<<<dim3(T), dim3(BLK), 0, stream>>>(
        hs, act, rnw, w_router, w_pred, w_corr, oscale, out, T);
}